// Round 3
// baseline (2590.382 us; speedup 1.0000x reference)
//
#include <hip/hip_runtime.h>
#include <math.h>

#define N_NODES 50000
#define N_EDGES 800000
#define HDIM 128
#define EPSV 1e-8f

typedef __attribute__((ext_vector_type(8))) short bf16x8;
typedef __attribute__((ext_vector_type(4))) float f32x4;

__device__ __forceinline__ float silu_(float x){ return x / (1.0f + __expf(-x)); }
__device__ __forceinline__ float clip100(float x){ return fminf(fmaxf(x, -100.0f), 100.0f); }

// bf16 helpers
__device__ __forceinline__ unsigned short f2bf(float f){            // RNE
    unsigned int u = __float_as_uint(f);
    unsigned int r = (u + 0x7FFFu + ((u >> 16) & 1u)) >> 16;
    return (unsigned short)r;
}
__device__ __forceinline__ float bf2f(unsigned short b){
    return __uint_as_float(((unsigned int)b) << 16);
}
__device__ __forceinline__ unsigned int pack2bf(float lo, float hi){
    return (unsigned int)f2bf(lo) | ((unsigned int)f2bf(hi) << 16);
}

// split fp32 -> hi (truncated bf16) + lo (RNE bf16 of residual); a ~= hi+lo to ~2^-15 rel
__device__ __forceinline__ void split8(const float4& f0, const float4& f1, bf16x8& hi, bf16x8& lo){
    float a[8] = {f0.x,f0.y,f0.z,f0.w,f1.x,f1.y,f1.z,f1.w};
#pragma unroll
    for(int i=0;i<8;i++){
        unsigned int u = __float_as_uint(a[i]);
        hi[i] = (short)(u >> 16);
        float hf = __uint_as_float(u & 0xFFFF0000u);
        lo[i] = (short)f2bf(a[i] - hf);
    }
}

// ---------------- CSR build ----------------
__global__ void count_kernel(const int* __restrict__ senders, int* __restrict__ cursor){
    int e = blockIdx.x*256 + threadIdx.x;
    if(e < N_EDGES) atomicAdd(&cursor[senders[e]], 1);
}

__global__ __launch_bounds__(1024) void scan_kernel(int* __restrict__ cursor, int* __restrict__ offs){
    __shared__ int lds[1024];
    const int CH = 49;
    int t = threadIdx.x;
    int base = t*CH;
    int sum = 0;
    for(int i=0;i<CH;i++){ int idx = base+i; if(idx < N_NODES) sum += cursor[idx]; }
    lds[t] = sum; __syncthreads();
    for(int off=1; off<1024; off<<=1){
        int v = (t>=off)? lds[t-off] : 0;
        __syncthreads();
        lds[t] += v;
        __syncthreads();
    }
    int run = lds[t] - sum;
    for(int i=0;i<CH;i++){
        int idx = base+i;
        if(idx < N_NODES){
            int c = cursor[idx];
            offs[idx] = run;
            cursor[idx] = run;
            run += c;
        }
    }
    if(t==1023) offs[N_NODES] = lds[1023];
}

__global__ void scatter_kernel(const int* __restrict__ senders, int* __restrict__ cursor, int* __restrict__ eord){
    int e = blockIdx.x*256 + threadIdx.x;
    if(e < N_EDGES){
        int pos = atomicAdd(&cursor[senders[e]], 1);
        eord[pos] = e;
    }
}

// ---------------- v -> bf16 copy ----------------
__global__ __launch_bounds__(256) void cast_v_kernel(const float* __restrict__ v, unsigned int* __restrict__ vb){
    size_t i = (size_t)blockIdx.x*256 + threadIdx.x;
    size_t total = (size_t)N_NODES*384/8;
    if(i < total){
        const float4* src = (const float4*)(v + i*8);
        float4 a = src[0], b = src[1];
        uint4 o;
        o.x = pack2bf(a.x, a.y);
        o.y = pack2bf(a.z, a.w);
        o.z = pack2bf(b.x, b.y);
        o.w = pack2bf(b.z, b.w);
        ((uint4*)vb)[i] = o;
    }
}

// ---------------- weights -> transposed hi/lo bf16 ----------------
// For W (KxN) produce WT_hi/WT_lo in [N][K] layout (B-fragment = contiguous 16B).
__global__ __launch_bounds__(256) void cast_weights_kernel(
    const float* __restrict__ W1, const float* __restrict__ W2,
    const float* __restrict__ Wm1, const float* __restrict__ Wm2,
    unsigned short* __restrict__ w1th, unsigned short* __restrict__ w1tl,
    unsigned short* __restrict__ w2th, unsigned short* __restrict__ w2tl,
    unsigned short* __restrict__ wm1th, unsigned short* __restrict__ wm1tl,
    unsigned short* __restrict__ wm2th, unsigned short* __restrict__ wm2tl)
{
    int g = blockIdx.x*256 + threadIdx.x;
    const float* src; unsigned short *dh, *dl; int K, N, e;
    if(g < 16384){ src=W1; dh=w1th; dl=w1tl; K=128; N=128; e=g; }
    else if(g < 65536){ src=W2; dh=w2th; dl=w2tl; K=128; N=384; e=g-16384; }
    else if(g < 98304){ src=Wm1; dh=wm1th; dl=wm1tl; K=256; N=128; e=g-65536; }
    else if(g < 147456){ src=Wm2; dh=wm2th; dl=wm2tl; K=128; N=384; e=g-98304; }
    else return;
    int n = e % N, k = e / N;
    float wv = src[k*N + n];
    unsigned int u = __float_as_uint(wv);
    unsigned short hi = (unsigned short)(u >> 16);
    float hf = __uint_as_float(u & 0xFFFF0000u);
    unsigned short lo = f2bf(wv - hf);
    dh[n*K + k] = hi;
    dl[n*K + k] = lo;
}

// ---------------- x = silu(s@W1+b1)@W2+b2 via split-bf16 MFMA, output bf16 ----------------
// 64 nodes/block, 256 thr = 4 waves x 16 rows. h transits LDS as hi/lo bf16 [64][136].
__global__ __launch_bounds__(256) void mlp_x_mfma(
    const float* __restrict__ s,
    const unsigned short* __restrict__ w1th, const unsigned short* __restrict__ w1tl,
    const float* __restrict__ b1,
    const unsigned short* __restrict__ w2th, const unsigned short* __restrict__ w2tl,
    const float* __restrict__ b2,
    unsigned short* __restrict__ xb)
{
    __shared__ unsigned short hHi[64*136];
    __shared__ unsigned short hLo[64*136];
    int t = threadIdx.x;
    int w = t >> 6, l = t & 63, lg = l >> 4, lm = l & 15;
    int n0 = blockIdx.x * 64;
    int rowA = n0 + w*16 + lm;               // A row (loads)
    int rowAc = min(rowA, N_NODES-1);
    int rowD = w*16 + lg*4;                  // D rows = rowD + reg (block-local)

    f32x4 acc[8];
#pragma unroll
    for(int i=0;i<8;i++) acc[i] = (f32x4){0.f,0.f,0.f,0.f};

    // GEMM1: [64x128] = s @ W1
    for(int ks=0; ks<4; ks++){
        int kb = ks*32;
        const float4* pa = (const float4*)&s[(size_t)rowAc*128 + kb + lg*8];
        bf16x8 ah, al; split8(pa[0], pa[1], ah, al);
#pragma unroll
        for(int nt=0; nt<8; nt++){
            int col = nt*16 + lm;
            bf16x8 bh = *(const bf16x8*)&w1th[col*128 + kb + lg*8];
            bf16x8 bl = *(const bf16x8*)&w1tl[col*128 + kb + lg*8];
            acc[nt] = __builtin_amdgcn_mfma_f32_16x16x32_bf16(ah, bh, acc[nt], 0,0,0);
            acc[nt] = __builtin_amdgcn_mfma_f32_16x16x32_bf16(ah, bl, acc[nt], 0,0,0);
            acc[nt] = __builtin_amdgcn_mfma_f32_16x16x32_bf16(al, bh, acc[nt], 0,0,0);
        }
    }
    // h = silu(acc + b1) -> LDS hi/lo
#pragma unroll
    for(int nt=0; nt<8; nt++){
        int colD = nt*16 + lm;
        float bias = b1[colD];
#pragma unroll
        for(int reg=0; reg<4; reg++){
            float h = silu_(acc[nt][reg] + bias);
            unsigned int u = __float_as_uint(h);
            unsigned short hi = (unsigned short)(u>>16);
            float hf = __uint_as_float(u & 0xFFFF0000u);
            unsigned short lo = f2bf(h - hf);
            int idx = (rowD+reg)*136 + colD;
            hHi[idx] = hi; hLo[idx] = lo;
        }
    }
    __syncthreads();

    // GEMM2: x[64x384] = h @ W2, 3 col-chunks of 128
    int rowL = w*16 + lm;
    for(int cb=0; cb<3; cb++){
        f32x4 a2[8];
#pragma unroll
        for(int i=0;i<8;i++) a2[i] = (f32x4){0.f,0.f,0.f,0.f};
        for(int ks=0; ks<4; ks++){
            int kb = ks*32 + lg*8;
            bf16x8 ah = *(const bf16x8*)&hHi[rowL*136 + kb];
            bf16x8 al = *(const bf16x8*)&hLo[rowL*136 + kb];
#pragma unroll
            for(int nt=0; nt<8; nt++){
                int col = cb*128 + nt*16 + lm;
                bf16x8 bh = *(const bf16x8*)&w2th[col*128 + kb];
                bf16x8 bl = *(const bf16x8*)&w2tl[col*128 + kb];
                a2[nt] = __builtin_amdgcn_mfma_f32_16x16x32_bf16(ah, bh, a2[nt], 0,0,0);
                a2[nt] = __builtin_amdgcn_mfma_f32_16x16x32_bf16(ah, bl, a2[nt], 0,0,0);
                a2[nt] = __builtin_amdgcn_mfma_f32_16x16x32_bf16(al, bh, a2[nt], 0,0,0);
            }
        }
#pragma unroll
        for(int nt=0; nt<8; nt++){
            int colD = cb*128 + nt*16 + lm;
            float bias = b2[colD];
#pragma unroll
            for(int reg=0; reg<4; reg++){
                int n = n0 + rowD + reg;
                if(n < N_NODES) xb[(size_t)n*384 + colD] = f2bf(a2[nt][reg] + bias);
            }
        }
    }
}

// ---------------- edge gather + segment sum ----------------
__global__ __launch_bounds__(256) void edge_kernel(
    const float* __restrict__ s, const float* __restrict__ v,
    const float* __restrict__ dir, const float* __restrict__ Wij,
    const int* __restrict__ recv, const int* __restrict__ offs,
    const int* __restrict__ eord, const unsigned short* __restrict__ xb,
    const unsigned short* __restrict__ vb,
    float* __restrict__ out)
{
    __shared__ int sE[256];
    __shared__ int sR[256];
    __shared__ float red[4*128];
    int n = blockIdx.x;
    int t = threadIdx.x;
    int h = t & 127, sub = t >> 7;
    int start = offs[n], end = offs[n+1];
    float ds=0.f, dv0=0.f, dv1=0.f, dv2=0.f;

    for(int base = start; base < end; base += 256){
        int cnt = min(end - base, 256);
        __syncthreads();
        if(t < cnt) sE[t] = eord[base + t];
        __syncthreads();
        if(t < cnt) sR[t] = recv[sE[t]];
        __syncthreads();
        for(int j = sub; j < cnt; j += 2){
            int e = sE[j], r = sR[j];
            const float* wr = &Wij[(size_t)e*384];
            float w0 = __builtin_nontemporal_load(wr + h);
            float w1 = __builtin_nontemporal_load(wr + 128 + h);
            float w2 = __builtin_nontemporal_load(wr + 256 + h);
            float d0 = __builtin_nontemporal_load(dir + (size_t)e*3 + 0);
            float d1 = __builtin_nontemporal_load(dir + (size_t)e*3 + 1);
            float d2 = __builtin_nontemporal_load(dir + (size_t)e*3 + 2);
            const unsigned short* xr = &xb[(size_t)r*384];
            float x0 = bf2f(xr[h]), x1 = bf2f(xr[128+h]), x2 = bf2f(xr[256+h]);
            const unsigned short* vr = &vb[(size_t)r*384];
            float vv0 = bf2f(vr[h]), vv1 = bf2f(vr[128+h]), vv2 = bf2f(vr[256+h]);
            ds += w0*x0;
            float a = w1*x1, b = w2*x2;
            dv0 += a*d0 + b*vv0;
            dv1 += a*d1 + b*vv1;
            dv2 += a*d2 + b*vv2;
        }
    }

    if(sub == 1){
        red[h] = ds; red[128+h] = dv0; red[256+h] = dv1; red[384+h] = dv2;
    }
    __syncthreads();
    if(sub == 0){
        ds  += red[h];
        dv0 += red[128+h];
        dv1 += red[256+h];
        dv2 += red[384+h];
        out[(size_t)n*128 + h] = s[(size_t)n*128 + h] + clip100(ds);
        float* ov = out + (size_t)N_NODES*128;
        ov[((size_t)n*3+0)*128 + h] = v[((size_t)n*3+0)*128 + h] + clip100(dv0);
        ov[((size_t)n*3+1)*128 + h] = v[((size_t)n*3+1)*128 + h] + clip100(dv1);
        ov[((size_t)n*3+2)*128 + h] = v[((size_t)n*3+2)*128 + h] + clip100(dv2);
    }
}

// ---------------- vw = v_mid @ Wv ; v_l out; v_norm, vdot (fp32 VALU, unchanged) ----------------
__global__ __launch_bounds__(256) void vw_kernel(
    const float* __restrict__ dout, const float* __restrict__ Wv,
    float* __restrict__ vl, float* __restrict__ vnorm, float* __restrict__ vdot)
{
    __shared__ float smem[48*256];
    float* aC = smem;
    float* wC = smem + 1664;
    const float* vm_g = dout + (size_t)N_NODES*128;
    int t = threadIdx.x, tx = t&63, ty = t>>6;
    int r0 = blockIdx.x*48;

    float acc[12][4] = {};
    for(int kc=0; kc<4; kc++){
        __syncthreads();
        for(int f=t; f<48*32; f+=256){
            int row = f>>5, kk = f&31;
            int gr = r0 + row;
            aC[kk*52+row] = (gr < N_NODES*3)? vm_g[(size_t)gr*128 + kc*32 + kk] : 0.0f;
        }
        for(int f=t; f<32*256; f+=256){
            int kk = f>>8, c = f&255;
            wC[kk*256+c] = Wv[(size_t)(kc*32+kk)*256 + c];
        }
        __syncthreads();
        for(int kk=0;kk<32;kk++){
            float4 w  = *(const float4*)&wC[kk*256 + tx*4];
            float4 a0 = *(const float4*)&aC[kk*52 + ty*12];
            float4 a1 = *(const float4*)&aC[kk*52 + ty*12 + 4];
            float4 a2 = *(const float4*)&aC[kk*52 + ty*12 + 8];
            float av[12] = {a0.x,a0.y,a0.z,a0.w,a1.x,a1.y,a1.z,a1.w,a2.x,a2.y,a2.z,a2.w};
            float wv[4] = {w.x,w.y,w.z,w.w};
#pragma unroll
            for(int r=0;r<12;r++)
#pragma unroll
                for(int c=0;c<4;c++) acc[r][c] += av[r]*wv[c];
        }
    }
    __syncthreads();
#pragma unroll
    for(int r=0;r<12;r++){
        float4 o = make_float4(acc[r][0],acc[r][1],acc[r][2],acc[r][3]);
        *(float4*)&smem[(ty*12+r)*256 + tx*4] = o;
    }
    __syncthreads();
    for(int f=t; f<48*128; f+=256){
        int row = f>>7, c = f&127;
        int gr = r0 + row;
        if(gr < N_NODES*3) vl[(size_t)gr*128 + c] = smem[row*256 + c];
    }
    for(int f=t; f<16*128; f+=256){
        int nl = f>>7, hc = f&127;
        int n = r0/3 + nl;
        if(n < N_NODES){
            float l0 = smem[(nl*3+0)*256 + hc], l1 = smem[(nl*3+1)*256 + hc], l2 = smem[(nl*3+2)*256 + hc];
            float q0 = smem[(nl*3+0)*256 + 128 + hc], q1 = smem[(nl*3+1)*256 + 128 + hc], q2 = smem[(nl*3+2)*256 + 128 + hc];
            vnorm[(size_t)n*128 + hc] = sqrtf(q0*q0 + q1*q1 + q2*q2 + EPSV);
            vdot [(size_t)n*128 + hc] = l0*q0 + l1*q1 + l2*q2;
        }
    }
}

// ---------------- update MLP via split-bf16 MFMA + final outputs ----------------
__global__ __launch_bounds__(256) void update_mfma(
    const float* __restrict__ vnorm, const float* __restrict__ vdot,
    const float* __restrict__ vl,
    const unsigned short* __restrict__ wm1th, const unsigned short* __restrict__ wm1tl,
    const float* __restrict__ bm1,
    const unsigned short* __restrict__ wm2th, const unsigned short* __restrict__ wm2tl,
    const float* __restrict__ bm2,
    float* __restrict__ dout)
{
    __shared__ unsigned short hHi[64*136];
    __shared__ unsigned short hLo[64*136];
    int t = threadIdx.x;
    int w = t >> 6, l = t & 63, lg = l >> 4, lm = l & 15;
    int n0 = blockIdx.x*64;
    int rowA = n0 + w*16 + lm;
    int rowAc = min(rowA, N_NODES-1);
    int rowD = w*16 + lg*4;
    float* s_g = dout;
    float* v_g = dout + (size_t)N_NODES*128;

    f32x4 acc[8];
#pragma unroll
    for(int i=0;i<8;i++) acc[i] = (f32x4){0.f,0.f,0.f,0.f};

    // GEMM1: [64x128] = [s_mid | vnorm] @ Wm1  (K=256)
    for(int ks=0; ks<8; ks++){
        int kb = ks*32;
        const float* base = (kb < 128) ? &s_g[(size_t)rowAc*128 + kb] : &vnorm[(size_t)rowAc*128 + (kb-128)];
        const float4* pa = (const float4*)(base + lg*8);
        bf16x8 ah, al; split8(pa[0], pa[1], ah, al);
#pragma unroll
        for(int nt=0; nt<8; nt++){
            int col = nt*16 + lm;
            bf16x8 bh = *(const bf16x8*)&wm1th[col*256 + kb + lg*8];
            bf16x8 bl = *(const bf16x8*)&wm1tl[col*256 + kb + lg*8];
            acc[nt] = __builtin_amdgcn_mfma_f32_16x16x32_bf16(ah, bh, acc[nt], 0,0,0);
            acc[nt] = __builtin_amdgcn_mfma_f32_16x16x32_bf16(ah, bl, acc[nt], 0,0,0);
            acc[nt] = __builtin_amdgcn_mfma_f32_16x16x32_bf16(al, bh, acc[nt], 0,0,0);
        }
    }
#pragma unroll
    for(int nt=0; nt<8; nt++){
        int colD = nt*16 + lm;
        float bias = bm1[colD];
#pragma unroll
        for(int reg=0; reg<4; reg++){
            float h = silu_(acc[nt][reg] + bias);
            unsigned int u = __float_as_uint(h);
            unsigned short hi = (unsigned short)(u>>16);
            float hf = __uint_as_float(u & 0xFFFF0000u);
            unsigned short lo = f2bf(h - hf);
            int idx = (rowD+reg)*136 + colD;
            hHi[idx] = hi; hLo[idx] = lo;
        }
    }
    __syncthreads();

    // GEMM2: u[64x384] = h @ Wm2, 3 chunks; fused epilogue
    int rowL = w*16 + lm;
    float ds2[8][4];
    for(int cb=0; cb<3; cb++){
        f32x4 a2[8];
#pragma unroll
        for(int i=0;i<8;i++) a2[i] = (f32x4){0.f,0.f,0.f,0.f};
        for(int ks=0; ks<4; ks++){
            int kb = ks*32 + lg*8;
            bf16x8 ah = *(const bf16x8*)&hHi[rowL*136 + kb];
            bf16x8 al = *(const bf16x8*)&hLo[rowL*136 + kb];
#pragma unroll
            for(int nt=0; nt<8; nt++){
                int col = cb*128 + nt*16 + lm;
                bf16x8 bh = *(const bf16x8*)&wm2th[col*128 + kb];
                bf16x8 bl = *(const bf16x8*)&wm2tl[col*128 + kb];
                a2[nt] = __builtin_amdgcn_mfma_f32_16x16x32_bf16(ah, bh, a2[nt], 0,0,0);
                a2[nt] = __builtin_amdgcn_mfma_f32_16x16x32_bf16(ah, bl, a2[nt], 0,0,0);
                a2[nt] = __builtin_amdgcn_mfma_f32_16x16x32_bf16(al, bh, a2[nt], 0,0,0);
            }
        }
        if(cb == 0){
#pragma unroll
            for(int nt=0; nt<8; nt++){
                float bias = bm2[nt*16 + lm];
#pragma unroll
                for(int reg=0; reg<4; reg++) ds2[nt][reg] = a2[nt][reg] + bias;
            }
        } else if(cb == 1){
#pragma unroll
            for(int nt=0; nt<8; nt++){
                int colD = 128 + nt*16 + lm;
                float bias = bm2[colD];
#pragma unroll
                for(int reg=0; reg<4; reg++){
                    int n = n0 + rowD + reg;
                    if(n < N_NODES){
                        float a = a2[nt][reg] + bias;
                        int colh = nt*16 + lm;
#pragma unroll
                        for(int c3=0; c3<3; c3++){
                            size_t idx = ((size_t)n*3 + c3)*128 + colh;
                            v_g[idx] = v_g[idx] + clip100(vl[idx] * a);
                        }
                    }
                }
            }
        } else {
#pragma unroll
            for(int nt=0; nt<8; nt++){
                int colD = 256 + nt*16 + lm;
                float bias = bm2[colD];
#pragma unroll
                for(int reg=0; reg<4; reg++){
                    int n = n0 + rowD + reg;
                    if(n < N_NODES){
                        float a = a2[nt][reg] + bias;
                        int colh = nt*16 + lm;
                        size_t idx = (size_t)n*128 + colh;
                        s_g[idx] = s_g[idx] + clip100(ds2[nt][reg] + a * vdot[idx]);
                    }
                }
            }
        }
    }
}

extern "C" void kernel_launch(void* const* d_in, const int* in_sizes, int n_in,
                              void* d_out, int out_size, void* d_ws, size_t ws_size,
                              hipStream_t stream)
{
    const float* s    = (const float*)d_in[0];
    const float* v    = (const float*)d_in[1];
    const float* dir  = (const float*)d_in[2];
    const float* Wij  = (const float*)d_in[3];
    const int* senders   = (const int*)d_in[4];
    const int* receivers = (const int*)d_in[5];
    const float* W1  = (const float*)d_in[6];
    const float* b1  = (const float*)d_in[7];
    const float* W2  = (const float*)d_in[8];
    const float* b2  = (const float*)d_in[9];
    const float* Wm1 = (const float*)d_in[10];
    const float* bm1 = (const float*)d_in[11];
    const float* Wm2 = (const float*)d_in[12];
    const float* bm2 = (const float*)d_in[13];
    const float* Wv  = (const float*)d_in[14];
    float* out = (float*)d_out;

    char* ws = (char*)d_ws;
    unsigned short* xb = (unsigned short*)ws;                    ws += (size_t)N_NODES*384*2;
    unsigned short* vb = (unsigned short*)ws;                    ws += (size_t)N_NODES*384*2;
    float* vl_ws    = (float*)ws;                                ws += (size_t)N_NODES*384*4;
    float* vnorm_ws = (float*)ws;                                ws += (size_t)N_NODES*128*4;
    float* vdot_ws  = (float*)ws;                                ws += (size_t)N_NODES*128*4;
    unsigned short* w1th = (unsigned short*)ws;                  ws += 16384*2;
    unsigned short* w1tl = (unsigned short*)ws;                  ws += 16384*2;
    unsigned short* w2th = (unsigned short*)ws;                  ws += 49152*2;
    unsigned short* w2tl = (unsigned short*)ws;                  ws += 49152*2;
    unsigned short* wm1th = (unsigned short*)ws;                 ws += 32768*2;
    unsigned short* wm1tl = (unsigned short*)ws;                 ws += 32768*2;
    unsigned short* wm2th = (unsigned short*)ws;                 ws += 49152*2;
    unsigned short* wm2tl = (unsigned short*)ws;                 ws += 49152*2;
    int* offs   = (int*)ws;                                      ws += (N_NODES+1)*4;
    int* cursor = (int*)ws;                                      ws += N_NODES*4;
    int* eord   = (int*)ws;

    hipMemsetAsync(cursor, 0, N_NODES*sizeof(int), stream);
    cast_weights_kernel<<<576, 256, 0, stream>>>(W1, W2, Wm1, Wm2,
        w1th, w1tl, w2th, w2tl, wm1th, wm1tl, wm2th, wm2tl);
    count_kernel  <<<(N_EDGES+255)/256, 256, 0, stream>>>(senders, cursor);
    scan_kernel   <<<1, 1024, 0, stream>>>(cursor, offs);
    scatter_kernel<<<(N_EDGES+255)/256, 256, 0, stream>>>(senders, cursor, eord);
    cast_v_kernel <<<((N_NODES*384/8)+255)/256, 256, 0, stream>>>(v, (unsigned int*)vb);
    mlp_x_mfma    <<<(N_NODES+63)/64, 256, 0, stream>>>(s, w1th, w1tl, b1, w2th, w2tl, b2, xb);
    edge_kernel   <<<N_NODES, 256, 0, stream>>>(s, v, dir, Wij, receivers, offs, eord, xb, vb, out);
    vw_kernel     <<<(N_NODES+15)/16, 256, 0, stream>>>(out, Wv, vl_ws, vnorm_ws, vdot_ws);
    update_mfma   <<<(N_NODES+63)/64, 256, 0, stream>>>(vnorm_ws, vdot_ws, vl_ws,
        wm1th, wm1tl, bm1, wm2th, wm2tl, bm2, out);
}

// Round 4
// 2364.657 us; speedup vs baseline: 1.0955x; 1.0955x over previous
//
#include <hip/hip_runtime.h>
#include <math.h>

#define N_NODES 50000
#define N_EDGES 800000
#define HDIM 128
#define EPSV 1e-8f

typedef __attribute__((ext_vector_type(8))) short bf16x8;
typedef __attribute__((ext_vector_type(4))) short bf16x4;
typedef __attribute__((ext_vector_type(4))) float f32x4;

__device__ __forceinline__ float silu_(float x){ return x / (1.0f + __expf(-x)); }
__device__ __forceinline__ float clip100(float x){ return fminf(fmaxf(x, -100.0f), 100.0f); }

// bf16 helpers
__device__ __forceinline__ unsigned short f2bf(float f){            // RNE
    unsigned int u = __float_as_uint(f);
    unsigned int r = (u + 0x7FFFu + ((u >> 16) & 1u)) >> 16;
    return (unsigned short)r;
}
__device__ __forceinline__ float bf2f(unsigned short b){
    return __uint_as_float(((unsigned int)b) << 16);
}
__device__ __forceinline__ unsigned int pack2bf(float lo, float hi){
    return (unsigned int)f2bf(lo) | ((unsigned int)f2bf(hi) << 16);
}

// split fp32 -> hi (truncated bf16) + lo (RNE bf16 of residual); a ~= hi+lo to ~2^-15 rel
__device__ __forceinline__ void split8(const float4& f0, const float4& f1, bf16x8& hi, bf16x8& lo){
    float a[8] = {f0.x,f0.y,f0.z,f0.w,f1.x,f1.y,f1.z,f1.w};
#pragma unroll
    for(int i=0;i<8;i++){
        unsigned int u = __float_as_uint(a[i]);
        hi[i] = (short)(u >> 16);
        float hf = __uint_as_float(u & 0xFFFF0000u);
        lo[i] = (short)f2bf(a[i] - hf);
    }
}
__device__ __forceinline__ void split4(const float4& f0, bf16x4& hi, bf16x4& lo){
    float a[4] = {f0.x,f0.y,f0.z,f0.w};
#pragma unroll
    for(int i=0;i<4;i++){
        unsigned int u = __float_as_uint(a[i]);
        hi[i] = (short)(u >> 16);
        float hf = __uint_as_float(u & 0xFFFF0000u);
        lo[i] = (short)f2bf(a[i] - hf);
    }
}

// ---------------- CSR build ----------------
__global__ void count_kernel(const int* __restrict__ senders, int* __restrict__ cursor){
    int e = blockIdx.x*256 + threadIdx.x;
    if(e < N_EDGES) atomicAdd(&cursor[senders[e]], 1);
}

__global__ __launch_bounds__(1024) void scan_kernel(int* __restrict__ cursor, int* __restrict__ offs){
    __shared__ int lds[1024];
    const int CH = 49;
    int t = threadIdx.x;
    int base = t*CH;
    int sum = 0;
    for(int i=0;i<CH;i++){ int idx = base+i; if(idx < N_NODES) sum += cursor[idx]; }
    lds[t] = sum; __syncthreads();
    for(int off=1; off<1024; off<<=1){
        int v = (t>=off)? lds[t-off] : 0;
        __syncthreads();
        lds[t] += v;
        __syncthreads();
    }
    int run = lds[t] - sum;
    for(int i=0;i<CH;i++){
        int idx = base+i;
        if(idx < N_NODES){
            int c = cursor[idx];
            offs[idx] = run;
            cursor[idx] = run;
            run += c;
        }
    }
    if(t==1023) offs[N_NODES] = lds[1023];
}

__global__ void scatter_kernel(const int* __restrict__ senders, int* __restrict__ cursor, int* __restrict__ eord){
    int e = blockIdx.x*256 + threadIdx.x;
    if(e < N_EDGES){
        int pos = atomicAdd(&cursor[senders[e]], 1);
        eord[pos] = e;
    }
}

// ---------------- v -> bf16 copy ----------------
__global__ __launch_bounds__(256) void cast_v_kernel(const float* __restrict__ v, unsigned int* __restrict__ vb){
    size_t i = (size_t)blockIdx.x*256 + threadIdx.x;
    size_t total = (size_t)N_NODES*384/8;
    if(i < total){
        const float4* src = (const float4*)(v + i*8);
        float4 a = src[0], b = src[1];
        uint4 o;
        o.x = pack2bf(a.x, a.y);
        o.y = pack2bf(a.z, a.w);
        o.z = pack2bf(b.x, b.y);
        o.w = pack2bf(b.z, b.w);
        ((uint4*)vb)[i] = o;
    }
}

// ---------------- weights -> transposed hi/lo bf16 ([N][K] layout) ----------------
__global__ __launch_bounds__(256) void cast_weights_kernel(
    const float* __restrict__ W1, const float* __restrict__ W2,
    const float* __restrict__ Wm1, const float* __restrict__ Wm2,
    const float* __restrict__ Wv,
    unsigned short* __restrict__ w1th, unsigned short* __restrict__ w1tl,
    unsigned short* __restrict__ w2th, unsigned short* __restrict__ w2tl,
    unsigned short* __restrict__ wm1th, unsigned short* __restrict__ wm1tl,
    unsigned short* __restrict__ wm2th, unsigned short* __restrict__ wm2tl,
    unsigned short* __restrict__ wvth, unsigned short* __restrict__ wvtl)
{
    int g = blockIdx.x*256 + threadIdx.x;
    const float* src; unsigned short *dh, *dl; int K, N, e;
    if(g < 16384){ src=W1; dh=w1th; dl=w1tl; K=128; N=128; e=g; }
    else if(g < 65536){ src=W2; dh=w2th; dl=w2tl; K=128; N=384; e=g-16384; }
    else if(g < 98304){ src=Wm1; dh=wm1th; dl=wm1tl; K=256; N=128; e=g-65536; }
    else if(g < 147456){ src=Wm2; dh=wm2th; dl=wm2tl; K=128; N=384; e=g-98304; }
    else if(g < 180224){ src=Wv; dh=wvth; dl=wvtl; K=128; N=256; e=g-147456; }
    else return;
    int n = e % N, k = e / N;
    float wv = src[k*N + n];
    unsigned int u = __float_as_uint(wv);
    unsigned short hi = (unsigned short)(u >> 16);
    float hf = __uint_as_float(u & 0xFFFF0000u);
    unsigned short lo = f2bf(wv - hf);
    dh[n*K + k] = hi;
    dl[n*K + k] = lo;
}

// ---------------- x = silu(s@W1+b1)@W2+b2 via split-bf16 MFMA (B LDS-staged), out bf16 ----------------
// 64 nodes/block, 256 thr = 4 waves x 16 rows.
__global__ __launch_bounds__(256) void mlp_x_mfma(
    const float* __restrict__ s,
    const unsigned short* __restrict__ w1th, const unsigned short* __restrict__ w1tl,
    const float* __restrict__ b1,
    const unsigned short* __restrict__ w2th, const unsigned short* __restrict__ w2tl,
    const float* __restrict__ b2,
    unsigned short* __restrict__ xb)
{
    __shared__ unsigned short hHi[64*136];
    __shared__ unsigned short hLo[64*136];
    __shared__ unsigned short bHi[128*40];
    __shared__ unsigned short bLo[128*40];
    int t = threadIdx.x;
    int w = t >> 6, l = t & 63, lg = l >> 4, lm = l & 15;
    int n0 = blockIdx.x * 64;
    int rowA = n0 + w*16 + lm;
    int rowAc = min(rowA, N_NODES-1);
    int rowD = w*16 + lg*4;
    int rowL = w*16 + lm;

    f32x4 acc[8];
#pragma unroll
    for(int i=0;i<8;i++) acc[i] = (f32x4){0.f,0.f,0.f,0.f};

    // GEMM1: [64x128] = s @ W1
    for(int ks=0; ks<4; ks++){
        int kb = ks*32;
        __syncthreads();
        for(int f=t; f<128*4; f+=256){
            int col = f>>2, seg = f&3;
            *(bf16x8*)&bHi[col*40+seg*8] = *(const bf16x8*)&w1th[col*128 + kb + seg*8];
            *(bf16x8*)&bLo[col*40+seg*8] = *(const bf16x8*)&w1tl[col*128 + kb + seg*8];
        }
        __syncthreads();
        const float4* pa = (const float4*)&s[(size_t)rowAc*128 + kb + lg*8];
        bf16x8 ah, al; split8(pa[0], pa[1], ah, al);
#pragma unroll
        for(int nt=0; nt<8; nt++){
            int col = nt*16 + lm;
            bf16x8 bh = *(const bf16x8*)&bHi[col*40 + lg*8];
            bf16x8 bl = *(const bf16x8*)&bLo[col*40 + lg*8];
            acc[nt] = __builtin_amdgcn_mfma_f32_16x16x32_bf16(ah, bh, acc[nt], 0,0,0);
            acc[nt] = __builtin_amdgcn_mfma_f32_16x16x32_bf16(ah, bl, acc[nt], 0,0,0);
            acc[nt] = __builtin_amdgcn_mfma_f32_16x16x32_bf16(al, bh, acc[nt], 0,0,0);
        }
    }
    // h = silu(acc + b1) -> LDS hi/lo
#pragma unroll
    for(int nt=0; nt<8; nt++){
        int colD = nt*16 + lm;
        float bias = b1[colD];
#pragma unroll
        for(int reg=0; reg<4; reg++){
            float h = silu_(acc[nt][reg] + bias);
            unsigned int u = __float_as_uint(h);
            unsigned short hi = (unsigned short)(u>>16);
            float hf = __uint_as_float(u & 0xFFFF0000u);
            unsigned short lo = f2bf(h - hf);
            int idx = (rowD+reg)*136 + colD;
            hHi[idx] = hi; hLo[idx] = lo;
        }
    }
    // (no sync needed here: GEMM2's first staging barrier orders hHi writes vs reads)

    // GEMM2: x[64x384] = h @ W2, 3 col-chunks of 128
    for(int cb=0; cb<3; cb++){
        f32x4 a2[8];
#pragma unroll
        for(int i=0;i<8;i++) a2[i] = (f32x4){0.f,0.f,0.f,0.f};
        for(int ks=0; ks<4; ks++){
            int kb = ks*32;
            __syncthreads();
            for(int f=t; f<128*4; f+=256){
                int col = f>>2, seg = f&3;
                *(bf16x8*)&bHi[col*40+seg*8] = *(const bf16x8*)&w2th[(size_t)(cb*128+col)*128 + kb + seg*8];
                *(bf16x8*)&bLo[col*40+seg*8] = *(const bf16x8*)&w2tl[(size_t)(cb*128+col)*128 + kb + seg*8];
            }
            __syncthreads();
            bf16x8 ah = *(const bf16x8*)&hHi[rowL*136 + kb + lg*8];
            bf16x8 al = *(const bf16x8*)&hLo[rowL*136 + kb + lg*8];
#pragma unroll
            for(int nt=0; nt<8; nt++){
                int col = nt*16 + lm;
                bf16x8 bh = *(const bf16x8*)&bHi[col*40 + lg*8];
                bf16x8 bl = *(const bf16x8*)&bLo[col*40 + lg*8];
                a2[nt] = __builtin_amdgcn_mfma_f32_16x16x32_bf16(ah, bh, a2[nt], 0,0,0);
                a2[nt] = __builtin_amdgcn_mfma_f32_16x16x32_bf16(ah, bl, a2[nt], 0,0,0);
                a2[nt] = __builtin_amdgcn_mfma_f32_16x16x32_bf16(al, bh, a2[nt], 0,0,0);
            }
        }
#pragma unroll
        for(int nt=0; nt<8; nt++){
            int colD = cb*128 + nt*16 + lm;
            float bias = b2[colD];
#pragma unroll
            for(int reg=0; reg<4; reg++){
                int n = n0 + rowD + reg;
                if(n < N_NODES) xb[(size_t)n*384 + colD] = f2bf(a2[nt][reg] + bias);
            }
        }
    }
}

// ---------------- edge gather + segment sum ----------------
__global__ __launch_bounds__(256) void edge_kernel(
    const float* __restrict__ s, const float* __restrict__ v,
    const float* __restrict__ dir, const float* __restrict__ Wij,
    const int* __restrict__ recv, const int* __restrict__ offs,
    const int* __restrict__ eord, const unsigned short* __restrict__ xb,
    const unsigned short* __restrict__ vb,
    float* __restrict__ out)
{
    __shared__ int sE[256];
    __shared__ int sR[256];
    __shared__ float red[4*128];
    int n = blockIdx.x;
    int t = threadIdx.x;
    int h = t & 127, sub = t >> 7;
    int start = offs[n], end = offs[n+1];
    float ds=0.f, dv0=0.f, dv1=0.f, dv2=0.f;

    for(int base = start; base < end; base += 256){
        int cnt = min(end - base, 256);
        __syncthreads();
        if(t < cnt) sE[t] = eord[base + t];
        __syncthreads();
        if(t < cnt) sR[t] = recv[sE[t]];
        __syncthreads();
        for(int j = sub; j < cnt; j += 2){
            int e = sE[j], r = sR[j];
            const float* wr = &Wij[(size_t)e*384];
            float w0 = __builtin_nontemporal_load(wr + h);
            float w1 = __builtin_nontemporal_load(wr + 128 + h);
            float w2 = __builtin_nontemporal_load(wr + 256 + h);
            float d0 = __builtin_nontemporal_load(dir + (size_t)e*3 + 0);
            float d1 = __builtin_nontemporal_load(dir + (size_t)e*3 + 1);
            float d2 = __builtin_nontemporal_load(dir + (size_t)e*3 + 2);
            const unsigned short* xr = &xb[(size_t)r*384];
            float x0 = bf2f(xr[h]), x1 = bf2f(xr[128+h]), x2 = bf2f(xr[256+h]);
            const unsigned short* vr = &vb[(size_t)r*384];
            float vv0 = bf2f(vr[h]), vv1 = bf2f(vr[128+h]), vv2 = bf2f(vr[256+h]);
            ds += w0*x0;
            float a = w1*x1, b = w2*x2;
            dv0 += a*d0 + b*vv0;
            dv1 += a*d1 + b*vv1;
            dv2 += a*d2 + b*vv2;
        }
    }

    if(sub == 1){
        red[h] = ds; red[128+h] = dv0; red[256+h] = dv1; red[384+h] = dv2;
    }
    __syncthreads();
    if(sub == 0){
        ds  += red[h];
        dv0 += red[128+h];
        dv1 += red[256+h];
        dv2 += red[384+h];
        out[(size_t)n*128 + h] = s[(size_t)n*128 + h] + clip100(ds);
        float* ov = out + (size_t)N_NODES*128;
        ov[((size_t)n*3+0)*128 + h] = v[((size_t)n*3+0)*128 + h] + clip100(dv0);
        ov[((size_t)n*3+1)*128 + h] = v[((size_t)n*3+1)*128 + h] + clip100(dv1);
        ov[((size_t)n*3+2)*128 + h] = v[((size_t)n*3+2)*128 + h] + clip100(dv2);
    }
}

// ---------------- vw = v_mid @ Wv via split-bf16 MFMA; v_l, v_norm, vdot ----------------
// 48 rows (16 nodes) per block, 256 thr = 4 waves. A+B staged hi/lo in LDS.
// Epilogue through [48][260] f32 LDS tile (union with staging buffers).
__global__ __launch_bounds__(256) void vw_mfma(
    const float* __restrict__ dout,
    const unsigned short* __restrict__ wvth, const unsigned short* __restrict__ wvtl,
    float* __restrict__ vl, float* __restrict__ vnorm, float* __restrict__ vdot)
{
    __shared__ float smemF[48*260];                       // 49920 B
    unsigned short* aHi = (unsigned short*)smemF;         // [48][40]
    unsigned short* aLo = aHi + 48*40;
    unsigned short* bHi = aLo + 48*40;                    // [256][40]
    unsigned short* bLo = bHi + 256*40;
    const float* vm_g = dout + (size_t)N_NODES*128;
    int t = threadIdx.x;
    int w = t>>6, l = t&63, lg = l>>4, lm = l&15;
    int r0 = blockIdx.x*48;                               // 150000 = 3125*48 exact

    f32x4 acc[3][4];
#pragma unroll
    for(int rt=0;rt<3;rt++)
#pragma unroll
        for(int ct=0;ct<4;ct++) acc[rt][ct] = (f32x4){0.f,0.f,0.f,0.f};

    for(int ks=0; ks<4; ks++){
        int kb = ks*32;
        __syncthreads();
        // stage A: 48 rows x 32 k, split hi/lo
        for(int f=t; f<48*8; f+=256){
            int row = f>>3, seg = f&7;
            float4 a = *(const float4*)&vm_g[(size_t)(r0+row)*128 + kb + seg*4];
            bf16x4 h4, l4; split4(a, h4, l4);
            *(bf16x4*)&aHi[row*40 + seg*4] = h4;
            *(bf16x4*)&aLo[row*40 + seg*4] = l4;
        }
        // stage B: 256 cols x 32 k
        for(int f=t; f<256*4; f+=256){
            int col = f>>2, seg = f&3;
            *(bf16x8*)&bHi[col*40+seg*8] = *(const bf16x8*)&wvth[col*128 + kb + seg*8];
            *(bf16x8*)&bLo[col*40+seg*8] = *(const bf16x8*)&wvtl[col*128 + kb + seg*8];
        }
        __syncthreads();
#pragma unroll
        for(int rt=0; rt<3; rt++){
            bf16x8 ah = *(const bf16x8*)&aHi[(rt*16+lm)*40 + lg*8];
            bf16x8 al = *(const bf16x8*)&aLo[(rt*16+lm)*40 + lg*8];
#pragma unroll
            for(int ct=0; ct<4; ct++){
                int col = (w*4+ct)*16 + lm;
                bf16x8 bh = *(const bf16x8*)&bHi[col*40 + lg*8];
                bf16x8 bl = *(const bf16x8*)&bLo[col*40 + lg*8];
                acc[rt][ct] = __builtin_amdgcn_mfma_f32_16x16x32_bf16(ah, bh, acc[rt][ct], 0,0,0);
                acc[rt][ct] = __builtin_amdgcn_mfma_f32_16x16x32_bf16(ah, bl, acc[rt][ct], 0,0,0);
                acc[rt][ct] = __builtin_amdgcn_mfma_f32_16x16x32_bf16(al, bh, acc[rt][ct], 0,0,0);
            }
        }
    }
    __syncthreads();   // staging buffers dead; reuse as f32 out tile
#pragma unroll
    for(int rt=0; rt<3; rt++)
#pragma unroll
        for(int ct=0; ct<4; ct++){
            int col = (w*4+ct)*16 + lm;
#pragma unroll
            for(int reg=0; reg<4; reg++){
                int row = rt*16 + lg*4 + reg;
                smemF[row*260 + col] = acc[rt][ct][reg];
            }
        }
    __syncthreads();
    // v_l (cols 0..127) -> global, float4
    for(int f=t; f<48*32; f+=256){
        int row = f>>5, c4 = (f&31)*4;
        *(float4*)&vl[(size_t)(r0+row)*128 + c4] = *(const float4*)&smemF[row*260 + c4];
    }
    // v_norm / vdot
    for(int f=t; f<16*128; f+=256){
        int nl = f>>7, hc = f&127;
        int n = r0/3 + nl;
        float l0 = smemF[(nl*3+0)*260 + hc], l1 = smemF[(nl*3+1)*260 + hc], l2 = smemF[(nl*3+2)*260 + hc];
        float q0 = smemF[(nl*3+0)*260 + 128 + hc], q1 = smemF[(nl*3+1)*260 + 128 + hc], q2 = smemF[(nl*3+2)*260 + 128 + hc];
        vnorm[(size_t)n*128 + hc] = sqrtf(q0*q0 + q1*q1 + q2*q2 + EPSV);
        vdot [(size_t)n*128 + hc] = l0*q0 + l1*q1 + l2*q2;
    }
}

// ---------------- update MLP via split-bf16 MFMA (B LDS-staged) + final outputs ----------------
__global__ __launch_bounds__(256) void update_mfma(
    const float* __restrict__ vnorm, const float* __restrict__ vdot,
    const float* __restrict__ vl,
    const unsigned short* __restrict__ wm1th, const unsigned short* __restrict__ wm1tl,
    const float* __restrict__ bm1,
    const unsigned short* __restrict__ wm2th, const unsigned short* __restrict__ wm2tl,
    const float* __restrict__ bm2,
    float* __restrict__ dout)
{
    __shared__ unsigned short hHi[64*136];
    __shared__ unsigned short hLo[64*136];
    __shared__ unsigned short bHi[128*40];
    __shared__ unsigned short bLo[128*40];
    int t = threadIdx.x;
    int w = t >> 6, l = t & 63, lg = l >> 4, lm = l & 15;
    int n0 = blockIdx.x*64;
    int rowA = n0 + w*16 + lm;
    int rowAc = min(rowA, N_NODES-1);
    int rowD = w*16 + lg*4;
    int rowL = w*16 + lm;
    float* s_g = dout;
    float* v_g = dout + (size_t)N_NODES*128;

    f32x4 acc[8];
#pragma unroll
    for(int i=0;i<8;i++) acc[i] = (f32x4){0.f,0.f,0.f,0.f};

    // GEMM1: [64x128] = [s_mid | vnorm] @ Wm1  (K=256)
    for(int ks=0; ks<8; ks++){
        int kb = ks*32;
        __syncthreads();
        for(int f=t; f<128*4; f+=256){
            int col = f>>2, seg = f&3;
            *(bf16x8*)&bHi[col*40+seg*8] = *(const bf16x8*)&wm1th[(size_t)col*256 + kb + seg*8];
            *(bf16x8*)&bLo[col*40+seg*8] = *(const bf16x8*)&wm1tl[(size_t)col*256 + kb + seg*8];
        }
        __syncthreads();
        const float* base = (kb < 128) ? &s_g[(size_t)rowAc*128 + kb] : &vnorm[(size_t)rowAc*128 + (kb-128)];
        const float4* pa = (const float4*)(base + lg*8);
        bf16x8 ah, al; split8(pa[0], pa[1], ah, al);
#pragma unroll
        for(int nt=0; nt<8; nt++){
            int col = nt*16 + lm;
            bf16x8 bh = *(const bf16x8*)&bHi[col*40 + lg*8];
            bf16x8 bl = *(const bf16x8*)&bLo[col*40 + lg*8];
            acc[nt] = __builtin_amdgcn_mfma_f32_16x16x32_bf16(ah, bh, acc[nt], 0,0,0);
            acc[nt] = __builtin_amdgcn_mfma_f32_16x16x32_bf16(ah, bl, acc[nt], 0,0,0);
            acc[nt] = __builtin_amdgcn_mfma_f32_16x16x32_bf16(al, bh, acc[nt], 0,0,0);
        }
    }
#pragma unroll
    for(int nt=0; nt<8; nt++){
        int colD = nt*16 + lm;
        float bias = bm1[colD];
#pragma unroll
        for(int reg=0; reg<4; reg++){
            float h = silu_(acc[nt][reg] + bias);
            unsigned int u = __float_as_uint(h);
            unsigned short hi = (unsigned short)(u>>16);
            float hf = __uint_as_float(u & 0xFFFF0000u);
            unsigned short lo = f2bf(h - hf);
            int idx = (rowD+reg)*136 + colD;
            hHi[idx] = hi; hLo[idx] = lo;
        }
    }

    // GEMM2: u[64x384] = h @ Wm2, 3 chunks; fused epilogue
    float ds2[8][4];
    for(int cb=0; cb<3; cb++){
        f32x4 a2[8];
#pragma unroll
        for(int i=0;i<8;i++) a2[i] = (f32x4){0.f,0.f,0.f,0.f};
        for(int ks=0; ks<4; ks++){
            int kb = ks*32;
            __syncthreads();
            for(int f=t; f<128*4; f+=256){
                int col = f>>2, seg = f&3;
                *(bf16x8*)&bHi[col*40+seg*8] = *(const bf16x8*)&wm2th[(size_t)(cb*128+col)*128 + kb + seg*8];
                *(bf16x8*)&bLo[col*40+seg*8] = *(const bf16x8*)&wm2tl[(size_t)(cb*128+col)*128 + kb + seg*8];
            }
            __syncthreads();
            bf16x8 ah = *(const bf16x8*)&hHi[rowL*136 + kb + lg*8];
            bf16x8 al = *(const bf16x8*)&hLo[rowL*136 + kb + lg*8];
#pragma unroll
            for(int nt=0; nt<8; nt++){
                int col = nt*16 + lm;
                bf16x8 bh = *(const bf16x8*)&bHi[col*40 + lg*8];
                bf16x8 bl = *(const bf16x8*)&bLo[col*40 + lg*8];
                a2[nt] = __builtin_amdgcn_mfma_f32_16x16x32_bf16(ah, bh, a2[nt], 0,0,0);
                a2[nt] = __builtin_amdgcn_mfma_f32_16x16x32_bf16(ah, bl, a2[nt], 0,0,0);
                a2[nt] = __builtin_amdgcn_mfma_f32_16x16x32_bf16(al, bh, a2[nt], 0,0,0);
            }
        }
        if(cb == 0){
#pragma unroll
            for(int nt=0; nt<8; nt++){
                float bias = bm2[nt*16 + lm];
#pragma unroll
                for(int reg=0; reg<4; reg++) ds2[nt][reg] = a2[nt][reg] + bias;
            }
        } else if(cb == 1){
#pragma unroll
            for(int nt=0; nt<8; nt++){
                int colD = 128 + nt*16 + lm;
                float bias = bm2[colD];
#pragma unroll
                for(int reg=0; reg<4; reg++){
                    int n = n0 + rowD + reg;
                    if(n < N_NODES){
                        float a = a2[nt][reg] + bias;
                        int colh = nt*16 + lm;
#pragma unroll
                        for(int c3=0; c3<3; c3++){
                            size_t idx = ((size_t)n*3 + c3)*128 + colh;
                            v_g[idx] = v_g[idx] + clip100(vl[idx] * a);
                        }
                    }
                }
            }
        } else {
#pragma unroll
            for(int nt=0; nt<8; nt++){
                int colD = 256 + nt*16 + lm;
                float bias = bm2[colD];
#pragma unroll
                for(int reg=0; reg<4; reg++){
                    int n = n0 + rowD + reg;
                    if(n < N_NODES){
                        float a = a2[nt][reg] + bias;
                        int colh = nt*16 + lm;
                        size_t idx = (size_t)n*128 + colh;
                        s_g[idx] = s_g[idx] + clip100(ds2[nt][reg] + a * vdot[idx]);
                    }
                }
            }
        }
    }
}

extern "C" void kernel_launch(void* const* d_in, const int* in_sizes, int n_in,
                              void* d_out, int out_size, void* d_ws, size_t ws_size,
                              hipStream_t stream)
{
    const float* s    = (const float*)d_in[0];
    const float* v    = (const float*)d_in[1];
    const float* dir  = (const float*)d_in[2];
    const float* Wij  = (const float*)d_in[3];
    const int* senders   = (const int*)d_in[4];
    const int* receivers = (const int*)d_in[5];
    const float* W1  = (const float*)d_in[6];
    const float* b1  = (const float*)d_in[7];
    const float* W2  = (const float*)d_in[8];
    const float* b2  = (const float*)d_in[9];
    const float* Wm1 = (const float*)d_in[10];
    const float* bm1 = (const float*)d_in[11];
    const float* Wm2 = (const float*)d_in[12];
    const float* bm2 = (const float*)d_in[13];
    const float* Wv  = (const float*)d_in[14];
    float* out = (float*)d_out;

    char* ws = (char*)d_ws;
    unsigned short* xb = (unsigned short*)ws;                    ws += (size_t)N_NODES*384*2;
    unsigned short* vb = (unsigned short*)ws;                    ws += (size_t)N_NODES*384*2;
    float* vl_ws    = (float*)ws;                                ws += (size_t)N_NODES*384*4;
    float* vnorm_ws = (float*)ws;                                ws += (size_t)N_NODES*128*4;
    float* vdot_ws  = (float*)ws;                                ws += (size_t)N_NODES*128*4;
    unsigned short* w1th = (unsigned short*)ws;                  ws += 16384*2;
    unsigned short* w1tl = (unsigned short*)ws;                  ws += 16384*2;
    unsigned short* w2th = (unsigned short*)ws;                  ws += 49152*2;
    unsigned short* w2tl = (unsigned short*)ws;                  ws += 49152*2;
    unsigned short* wm1th = (unsigned short*)ws;                 ws += 32768*2;
    unsigned short* wm1tl = (unsigned short*)ws;                 ws += 32768*2;
    unsigned short* wm2th = (unsigned short*)ws;                 ws += 49152*2;
    unsigned short* wm2tl = (unsigned short*)ws;                 ws += 49152*2;
    unsigned short* wvth = (unsigned short*)ws;                  ws += 32768*2;
    unsigned short* wvtl = (unsigned short*)ws;                  ws += 32768*2;
    int* offs   = (int*)ws;                                      ws += (N_NODES+1)*4;
    int* cursor = (int*)ws;                                      ws += N_NODES*4;
    int* eord   = (int*)ws;

    hipMemsetAsync(cursor, 0, N_NODES*sizeof(int), stream);
    cast_weights_kernel<<<704, 256, 0, stream>>>(W1, W2, Wm1, Wm2, Wv,
        w1th, w1tl, w2th, w2tl, wm1th, wm1tl, wm2th, wm2tl, wvth, wvtl);
    count_kernel  <<<(N_EDGES+255)/256, 256, 0, stream>>>(senders, cursor);
    scan_kernel   <<<1, 1024, 0, stream>>>(cursor, offs);
    scatter_kernel<<<(N_EDGES+255)/256, 256, 0, stream>>>(senders, cursor, eord);
    cast_v_kernel <<<((N_NODES*384/8)+255)/256, 256, 0, stream>>>(v, (unsigned int*)vb);
    mlp_x_mfma    <<<(N_NODES+63)/64, 256, 0, stream>>>(s, w1th, w1tl, b1, w2th, w2tl, b2, xb);
    edge_kernel   <<<N_NODES, 256, 0, stream>>>(s, v, dir, Wij, receivers, offs, eord, xb, vb, out);
    vw_mfma       <<<3125, 256, 0, stream>>>(out, wvth, wvtl, vl_ws, vnorm_ws, vdot_ws);
    update_mfma   <<<(N_NODES+63)/64, 256, 0, stream>>>(vnorm_ws, vdot_ws, vl_ws,
        wm1th, wm1tl, bm1, wm2th, wm2tl, bm2, out);
}